// Round 8
// baseline (762.797 us; speedup 1.0000x reference)
//
#include <hip/hip_runtime.h>
#include <hip/hip_bf16.h>

#define DM 1024
#define NH 16
#define DH 64
#define DFF 4096
#define NBATCH 2
#define SEQL 2048
#define MTOK (NBATCH*SEQL)

typedef float f32x4 __attribute__((ext_vector_type(4)));
typedef __bf16 bf16x8 __attribute__((ext_vector_type(8)));
typedef unsigned short u16;
typedef unsigned int u32;
typedef unsigned short u16x4 __attribute__((ext_vector_type(4)));
typedef unsigned short u16x8 __attribute__((ext_vector_type(8)));
typedef unsigned int u32x4 __attribute__((ext_vector_type(4)));

__device__ __forceinline__ u16 f2bf(float f) {
    u32 u = __builtin_bit_cast(u32, f);
    return (u16)((u + 0x7fffu + ((u >> 16) & 1u)) >> 16);
}
__device__ __forceinline__ float bf2f(u16 h) {
    return __builtin_bit_cast(float, (u32)h << 16);
}
__device__ __forceinline__ f32x4 mfma16(bf16x8 a, bf16x8 b, f32x4 c) {
    return __builtin_amdgcn_mfma_f32_16x16x32_bf16(a, b, c, 0, 0, 0);
}
// async global->LDS, 16B per lane. LDS dest = wave-uniform base + lane*16.
__device__ __forceinline__ void gload16(const void* g, void* l) {
    __builtin_amdgcn_global_load_lds(
        (const __attribute__((address_space(1))) unsigned int*)g,
        (__attribute__((address_space(3))) unsigned int*)l, 16, 0, 0);
}
// XCD-aware bijective swizzle (T1): physical block p runs on XCD p%8; give
// each XCD a CONTIGUOUS chunk of logical work so co-resident blocks share
// operand panels in that XCD's private L2. Requires nwg % 8 == 0 (all grids
// here are). m157/m192-verified formula.
__device__ __forceinline__ int xcd_swz(int p, int nwg) {
    return (p & 7) * (nwg >> 3) + (p >> 3);
}
// Counted-vmcnt barrier pair (T4): prefetch loads stay in flight across the
// barrier. "memory" clobbers = compiler fences (no ds_read hoist / gload sink).
#define WAIT_VM8_BAR  { asm volatile("s_waitcnt vmcnt(8)" ::: "memory"); \
                        asm volatile("s_barrier" ::: "memory"); }
#define WAIT_VM0_BAR  { asm volatile("s_waitcnt vmcnt(0)" ::: "memory"); \
                        asm volatile("s_barrier" ::: "memory"); }
#define LGKM0_BAR     { asm volatile("s_waitcnt lgkmcnt(0)" ::: "memory"); \
                        asm volatile("s_barrier" ::: "memory"); }

// ---------------------------------------------------------------------------
// GEMM core v4: C[128x128] tile of A[M,K](bf16 hi/lo) @ B[N,K](bf16 hi/lo)^T.
// BK=32, double-buffered LDS (4 arrays x 2 bufs x 8KB = 64KB).
// Counted-vmcnt pipeline: stage(t+1) [8 loads/thread]; s_waitcnt vmcnt(8)
// waits only the 8 OLDEST (= tile t, FIFO); s_barrier; compute(t) while the
// t+1 loads remain in flight; lgkmcnt(0)+s_barrier closes the buf-reuse
// window. Conflict-free swizzle (r6-verified, conflicts==0): 16B chunk c of
// row r stored at c ^ ((r>>1)&3); global source pre-swizzled (both-sides).
// Split fp32 = bf16_hi + bf16_lo; product via 3 MFMAs (drop lo*lo ~2^-18).
// ---------------------------------------------------------------------------
__device__ __forceinline__ void gemm_core(
    const u16* __restrict__ Ah, const u16* __restrict__ Al,
    const u16* __restrict__ Bh, const u16* __restrict__ Bl,
    int K, int m0, int n0,
    u16* lsAh, u16* lsAl, u16* lsBh, u16* lsBl,   // each [2][128*32]
    f32x4 acc[4][4])
{
    const int t = threadIdx.x;
    const int lane = t & 63;
    const int wv = t >> 6;
    const int wm = ((t >> 7) & 1) * 64;
    const int wn = ((t >> 6) & 1) * 64;
    const int lrow = lane & 15;
    const int lk = lane >> 4;
    const f32x4 FZ = {0.f, 0.f, 0.f, 0.f};
#pragma unroll
    for (int i = 0; i < 4; ++i)
#pragma unroll
        for (int j = 0; j < 4; ++j) acc[i][j] = FZ;

    const int NT = K >> 5;
    const int rsub = lane >> 2;
    const int gchk = ((lane & 3) ^ ((lane >> 3) & 3)) * 8;   // k-offset, elems
    const int rsw = (lk ^ ((lrow >> 1) & 3)) * 8;

    auto stage = [&](int buf, int kt) {
        const int k0 = kt << 5;
#pragma unroll
        for (int p = 0; p < 2; ++p) {
            const int seg = wv * 2 + p;   // 8 segments of 16 rows
            const int row = seg * 16 + rsub;
            const size_t sa = (size_t)(m0 + row) * K + k0 + gchk;
            const size_t sb = (size_t)(n0 + row) * K + k0 + gchk;
            const int d = buf * 4096 + seg * 512;
            gload16(Ah + sa, lsAh + d);
            gload16(Al + sa, lsAl + d);
            gload16(Bh + sb, lsBh + d);
            gload16(Bl + sb, lsBl + d);
        }
    };

    stage(0, 0);
    int buf = 0;
    for (int kt = 0; kt < NT; ++kt) {
        if (kt + 1 < NT) {
            stage(buf ^ 1, kt + 1);
            WAIT_VM8_BAR
        } else {
            WAIT_VM0_BAR
        }
        bf16x8 ah[4], al[4], bh[4], bl[4];
#pragma unroll
        for (int i = 0; i < 4; ++i) {
            const int ia = buf * 4096 + (wm + i * 16 + lrow) * 32 + rsw;
            ah[i] = *reinterpret_cast<const bf16x8*>(&lsAh[ia]);
            al[i] = *reinterpret_cast<const bf16x8*>(&lsAl[ia]);
            const int ib = buf * 4096 + (wn + i * 16 + lrow) * 32 + rsw;
            bh[i] = *reinterpret_cast<const bf16x8*>(&lsBh[ib]);
            bl[i] = *reinterpret_cast<const bf16x8*>(&lsBl[ib]);
        }
        __builtin_amdgcn_s_setprio(1);
#pragma unroll
        for (int i = 0; i < 4; ++i)
#pragma unroll
            for (int j = 0; j < 4; ++j) {
                acc[i][j] = mfma16(ah[i], bh[j], acc[i][j]);
                acc[i][j] = mfma16(al[i], bh[j], acc[i][j]);
                acc[i][j] = mfma16(ah[i], bl[j], acc[i][j]);
            }
        __builtin_amdgcn_s_setprio(0);
        LGKM0_BAR
        buf ^= 1;
    }
}

#define GEMM_LDS \
    __shared__ __align__(16) u16 lsAh[2 * 4096], lsAl[2 * 4096], \
                                 lsBh[2 * 4096], lsBl[2 * 4096];

// C/D frag mapping (HW-verified m89): col = lane&15, row = (lane>>4)*4 + r
template <class F>
__device__ __forceinline__ void epilogue(const f32x4 acc[4][4], int m0, int n0, F f) {
    const int lane = threadIdx.x & 63;
    const int wm = ((threadIdx.x >> 7) & 1) * 64;
    const int wn = ((threadIdx.x >> 6) & 1) * 64;
#pragma unroll
    for (int i = 0; i < 4; ++i)
#pragma unroll
        for (int j = 0; j < 4; ++j)
#pragma unroll
            for (int r = 0; r < 4; ++r) {
                const int m = m0 + wm + i * 16 + ((lane >> 4) << 2) + r;
                const int o = n0 + wn + j * 16 + (lane & 15);
                f(m, o, acc[i][j][r]);
            }
}

// ---------------------------------------------------------------------------
// Merged weight split: one launch for all 7 matrices (saves 6 launch ramps).
// Blocks 0..2047: Wq/Wk/Wv/Wo (512 each); 2048..8191: W1/W2/W3 (2048 each).
struct WJobs { const float* s[7]; u16* h[7]; u16* l[7]; };
__global__ __launch_bounds__(256) void k_splitw_all(WJobs jobs)
{
    const int bid = blockIdx.x;
    int which, off;
    if (bid < 2048) { which = bid >> 9; off = bid & 511; }
    else { which = 4 + ((bid - 2048) >> 11); off = (bid - 2048) & 2047; }
    const float* __restrict__ src = jobs.s[which];
    u16* __restrict__ dh = jobs.h[which];
    u16* __restrict__ dl = jobs.l[which];
    const int i = (off * 256 + threadIdx.x) * 8;
    const f32x4 a = *reinterpret_cast<const f32x4*>(src + i);
    const f32x4 b = *reinterpret_cast<const f32x4*>(src + i + 4);
    u16x8 hh, ll;
#pragma unroll
    for (int e = 0; e < 4; ++e) {
        const u16 h0 = f2bf(a[e]);
        hh[e] = h0; ll[e] = f2bf(a[e] - bf2f(h0));
        const u16 h1 = f2bf(b[e]);
        hh[4 + e] = h1; ll[4 + e] = f2bf(b[e] - bf2f(h1));
    }
    *reinterpret_cast<u16x8*>(dh + i) = hh;
    *reinterpret_cast<u16x8*>(dl + i) = ll;
}

__global__ __launch_bounds__(256) void k_rmsnorm(
    const float* __restrict__ x, const float* __restrict__ g,
    u16* __restrict__ oh, u16* __restrict__ ol)
{
    const int row = blockIdx.x * 4 + (threadIdx.x >> 6);
    const int lane = threadIdx.x & 63;
    const float* xr = x + (size_t)row * DM;
    f32x4 v[4];
    float ss = 0.f;
#pragma unroll
    for (int j = 0; j < 4; ++j) {
        v[j] = *reinterpret_cast<const f32x4*>(&xr[(lane + j * 64) * 4]);
        ss += v[j][0] * v[j][0] + v[j][1] * v[j][1] + v[j][2] * v[j][2] + v[j][3] * v[j][3];
    }
#pragma unroll
    for (int off = 32; off > 0; off >>= 1) ss += __shfl_xor(ss, off, 64);
    const float sc = 1.0f / sqrtf(ss * (1.0f / (float)DM) + 1e-5f);
#pragma unroll
    for (int j = 0; j < 4; ++j) {
        const int c0 = (lane + j * 64) * 4;
        const f32x4 gv = *reinterpret_cast<const f32x4*>(&g[c0]);
        u16x4 hh, ll;
#pragma unroll
        for (int e = 0; e < 4; ++e) {
            const float y = v[j][e] * sc * gv[e];
            const u16 hi = f2bf(y);
            hh[e] = hi;
            ll[e] = f2bf(y - bf2f(hi));
        }
        *reinterpret_cast<u16x4*>(&oh[(size_t)row * DM + c0]) = hh;
        *reinterpret_cast<u16x4*>(&ol[(size_t)row * DM + c0]) = ll;
    }
}

// QKV: grid (32, 24). q,k in [B,H,S,dh]; v stored TRANSPOSED [B,H,dh,S].
__global__ __launch_bounds__(256, 2) void k_qkv(
    const u16* __restrict__ Ah, const u16* __restrict__ Al,
    const u16* __restrict__ swqh, const u16* __restrict__ swql,
    const u16* __restrict__ swkh, const u16* __restrict__ swkl,
    const u16* __restrict__ swvh, const u16* __restrict__ swvl,
    u16* __restrict__ qh, u16* __restrict__ ql, u16* __restrict__ kh, u16* __restrict__ kl,
    u16* __restrict__ vth, u16* __restrict__ vtl)
{
    GEMM_LDS
    const int swz = xcd_swz(blockIdx.y * 32 + blockIdx.x, 32 * 24);
    const int m0 = (swz & 31) * 128;
    const int ng = (swz >> 5) * 128;
    const int proj = ng >> 10;
    const int n0 = ng & 1023;
    const u16* Bh = (proj == 0) ? swqh : ((proj == 1) ? swkh : swvh);
    const u16* Bl = (proj == 0) ? swql : ((proj == 1) ? swkl : swvl);
    f32x4 acc[4][4];
    gemm_core(Ah, Al, Bh, Bl, DM, m0, n0, lsAh, lsAl, lsBh, lsBl, acc);
    if (proj < 2) {
        u16* oph = (proj == 0) ? qh : kh;
        u16* opl = (proj == 0) ? ql : kl;
        epilogue(acc, m0, n0, [&](int m, int o, float val) {
            const int b = m >> 11, s = m & (SEQL - 1);
            const int hd = o >> 6, d = o & 63;
            const size_t idx = (((size_t)b * NH + hd) * SEQL + s) * DH + d;
            const u16 hi = f2bf(val);
            oph[idx] = hi;
            opl[idx] = f2bf(val - bf2f(hi));
        });
    } else {
        epilogue(acc, m0, n0, [&](int m, int o, float val) {
            const int b = m >> 11, s = m & (SEQL - 1);
            const int hd = o >> 6, d = o & 63;
            const size_t idx = (((size_t)b * NH + hd) * DH + d) * SEQL + s;
            const u16 hi = f2bf(val);
            vth[idx] = hi;
            vtl[idx] = f2bf(val - bf2f(hi));
        });
    }
}

__global__ __launch_bounds__(256, 2) void k_oproj(
    const u16* __restrict__ Ah, const u16* __restrict__ Al,
    const u16* __restrict__ Bh, const u16* __restrict__ Bl,
    const float* __restrict__ xres, float* __restrict__ out)
{
    GEMM_LDS
    const int swz = xcd_swz(blockIdx.y * 32 + blockIdx.x, 32 * 8);
    const int m0 = (swz & 31) * 128;
    const int n0 = (swz >> 5) * 128;
    f32x4 acc[4][4];
    gemm_core(Ah, Al, Bh, Bl, DM, m0, n0, lsAh, lsAl, lsBh, lsBl, acc);
    epilogue(acc, m0, n0, [&](int m, int o, float val) {
        const size_t idx = (size_t)m * DM + o;
        out[idx] = xres[idx] + val;
    });
}

// Fused FFN1+FFN3: two K-loops over the same A (xn2), h = silu(h1)*h3
// written split once (no h1 round-trip). acc1 stays in registers.
__global__ __launch_bounds__(256, 2) void k_ffn13(
    const u16* __restrict__ Ah, const u16* __restrict__ Al,
    const u16* __restrict__ B1h, const u16* __restrict__ B1l,
    const u16* __restrict__ B3h, const u16* __restrict__ B3l,
    u16* __restrict__ hh, u16* __restrict__ hl)
{
    GEMM_LDS
    const int swz = xcd_swz(blockIdx.y * 32 + blockIdx.x, 32 * 32);
    const int m0 = (swz & 31) * 128;
    const int n0 = (swz >> 5) * 128;
    f32x4 acc1[4][4], acc3[4][4];
    gemm_core(Ah, Al, B1h, B1l, DM, m0, n0, lsAh, lsAl, lsBh, lsBl, acc1);
    gemm_core(Ah, Al, B3h, B3l, DM, m0, n0, lsAh, lsAl, lsBh, lsBl, acc3);
    const int lane = threadIdx.x & 63;
    const int wm = ((threadIdx.x >> 7) & 1) * 64;
    const int wn = ((threadIdx.x >> 6) & 1) * 64;
#pragma unroll
    for (int i = 0; i < 4; ++i)
#pragma unroll
        for (int j = 0; j < 4; ++j)
#pragma unroll
            for (int r = 0; r < 4; ++r) {
                const int m = m0 + wm + i * 16 + ((lane >> 4) << 2) + r;
                const int o = n0 + wn + j * 16 + (lane & 15);
                const float h1 = acc1[i][j][r];
                const float h3 = acc3[i][j][r];
                const float sg = 1.0f / (1.0f + expf(-h1));
                const float hv = h1 * sg * h3;
                const size_t idx = (size_t)m * DFF + o;
                const u16 hi = f2bf(hv);
                hh[idx] = hi;
                hl[idx] = f2bf(hv - bf2f(hi));
            }
}

__global__ __launch_bounds__(256, 2) void k_ffn2(
    const u16* __restrict__ Ah, const u16* __restrict__ Al,
    const u16* __restrict__ Bh, const u16* __restrict__ Bl,
    float* __restrict__ out)
{
    GEMM_LDS
    const int swz = xcd_swz(blockIdx.y * 32 + blockIdx.x, 32 * 8);
    const int m0 = (swz & 31) * 128;
    const int n0 = (swz >> 5) * 128;
    f32x4 acc[4][4];
    gemm_core(Ah, Al, Bh, Bl, DFF, m0, n0, lsAh, lsAl, lsBh, lsBl, acc);
    epilogue(acc, m0, n0, [&](int m, int o, float val) {
        const size_t idx = (size_t)m * DM + o;
        out[idx] = out[idx] + val;
    });
}

// ---------------------------------------------------------------------------
// Flash attention. Logical grid (16 pairs, 32 bh): pair pr covers q-tiles pr
// and 31-pr (64 rows each) => every block does exactly 33 KV-tile iterations.
// XCD swizzle gives each XCD 4 consecutive bh (4 MB KV = L2-resident).
// 4 waves, each owns 16 q-rows. K [kv][d] and V^T [d][kv] staged via
// global_load_lds, double-buffered, counted-vmcnt pipeline (same as GEMM).
// ---------------------------------------------------------------------------
__global__ __launch_bounds__(256) void k_attn(
    const u16* __restrict__ gqh, const u16* __restrict__ gql,
    const u16* __restrict__ gkh, const u16* __restrict__ gkl,
    const u16* __restrict__ gvth, const u16* __restrict__ gvtl,
    u16* __restrict__ aoh, u16* __restrict__ aol)
{
    __shared__ __align__(16) u16 sKh[2][4096], sKl[2][4096], sVh[2][4096], sVl[2][4096];
    __shared__ __align__(16) u32 Pw[4][16 * 64];
    const int t = threadIdx.x, lane = t & 63, wid = t >> 6;
    const int lrow = lane & 15, lk = lane >> 4;
    const int swz = xcd_swz(blockIdx.y * 16 + blockIdx.x, 16 * 32);
    const int pr = swz & 15;
    const int bh = swz >> 4;
    const size_t base = (size_t)bh * SEQL * DH;
    const f32x4 FZ = {0.f, 0.f, 0.f, 0.f};
    const int b = bh >> 4, hd = bh & 15;

    auto stage = [&](int buf, int kvt) {
        const int kv0 = kvt << 6;
#pragma unroll
        for (int p = 0; p < 2; ++p) {
            const int seg = wid * 2 + p;            // 0..7, 8 rows each
            const int row = seg * 8 + (lane >> 3);
            const int g = (lane & 7) ^ (row & 7);
            const size_t sk = base + (size_t)(kv0 + row) * DH + g * 8;
            const size_t sv = base + (size_t)row * SEQL + kv0 + g * 8;
            gload16(gkh + sk, &sKh[buf][seg * 512]);
            gload16(gkl + sk, &sKl[buf][seg * 512]);
            gload16(gvth + sv, &sVh[buf][seg * 512]);
            gload16(gvtl + sv, &sVl[buf][seg * 512]);
        }
    };

    for (int hf = 0; hf < 2; ++hf) {
        const int qt = hf ? (31 - pr) : pr;
        const int qw = qt * 64 + wid * 16;
        bf16x8 Qh[2], Ql[2];
#pragma unroll
        for (int ks = 0; ks < 2; ++ks) {
            const size_t off = base + (size_t)(qw + lrow) * DH + ks * 32 + lk * 8;
            Qh[ks] = *reinterpret_cast<const bf16x8*>(&gqh[off]);
            Ql[ks] = *reinterpret_cast<const bf16x8*>(&gql[off]);
        }
        float mr[4], lr[4];
        f32x4 Oa[4];
#pragma unroll
        for (int r = 0; r < 4; ++r) { mr[r] = -1.0e30f; lr[r] = 0.f; }
#pragma unroll
        for (int n = 0; n < 4; ++n) Oa[n] = FZ;

        const int ntile = qt + 1;
        stage(0, 0);
        int buf = 0;
        for (int kvt = 0; kvt < ntile; ++kvt) {
            if (kvt + 1 < ntile) {
                stage(buf ^ 1, kvt + 1);
                WAIT_VM8_BAR   // FIFO: waits tile-kvt loads (+ any older stores)
            } else {
                WAIT_VM0_BAR
            }
            const int kv0 = kvt << 6;
            // ---- QK^T ----
            f32x4 S[4];
#pragma unroll
            for (int nf = 0; nf < 4; ++nf) S[nf] = FZ;
#pragma unroll
            for (int ks = 0; ks < 2; ++ks) {
                bf16x8 kbh[4], kbl[4];
#pragma unroll
                for (int nf = 0; nf < 4; ++nf) {
                    const int row = nf * 16 + lrow;
                    const int idx = row * 64 + (((lk + ks * 4) ^ (row & 7)) << 3);
                    kbh[nf] = *reinterpret_cast<const bf16x8*>(&sKh[buf][idx]);
                    kbl[nf] = *reinterpret_cast<const bf16x8*>(&sKl[buf][idx]);
                }
                __builtin_amdgcn_s_setprio(1);
#pragma unroll
                for (int nf = 0; nf < 4; ++nf) {
                    S[nf] = mfma16(Qh[ks], kbh[nf], S[nf]);
                    S[nf] = mfma16(Ql[ks], kbh[nf], S[nf]);
                    S[nf] = mfma16(Qh[ks], kbl[nf], S[nf]);
                }
                __builtin_amdgcn_s_setprio(0);
            }
            // ---- online softmax (scale 1/8) ----
#pragma unroll
            for (int r = 0; r < 4; ++r) {
                const int qrow = qw + (lk << 2) + r;
                float rmx = -3.0e38f;
#pragma unroll
                for (int nf = 0; nf < 4; ++nf) {
                    const int col = kv0 + nf * 16 + lrow;
                    const float tv = (col <= qrow) ? S[nf][r] * 0.125f : -3.0e38f;
                    S[nf][r] = tv;
                    rmx = fmaxf(rmx, tv);
                }
#pragma unroll
                for (int off = 8; off > 0; off >>= 1) rmx = fmaxf(rmx, __shfl_xor(rmx, off, 16));
                const float mnew = fmaxf(mr[r], rmx);
                const float alpha = exp2f((mr[r] - mnew) * 1.44269504f);
                mr[r] = mnew;
                float rsum = 0.f;
#pragma unroll
                for (int nf = 0; nf < 4; ++nf) {
                    const float p = exp2f((S[nf][r] - mnew) * 1.44269504f);
                    S[nf][r] = p;
                    rsum += p;
                }
#pragma unroll
                for (int off = 8; off > 0; off >>= 1) rsum += __shfl_xor(rsum, off, 16);
                lr[r] = lr[r] * alpha + rsum;
#pragma unroll
                for (int n = 0; n < 4; ++n) Oa[n][r] *= alpha;
                const int prow = (lk << 2) + r;
#pragma unroll
                for (int nf = 0; nf < 4; ++nf) {
                    const float p = S[nf][r];
                    const u16 phi = f2bf(p);
                    const u16 plo = f2bf(p - bf2f(phi));
                    const int pcol = nf * 16 + lrow;
                    Pw[wid][prow * 64 + ((((pcol >> 3) ^ (prow & 7))) << 3) + (pcol & 7)] =
                        (u32)phi | ((u32)plo << 16);
                }
            }
            asm volatile("s_waitcnt lgkmcnt(0)" ::: "memory");
            // ---- P @ V (A-frag from Pw, B-frag from V^T tile) ----
#pragma unroll
            for (int ks = 0; ks < 2; ++ks) {
                const int row = lrow;
                const int c = (lk + ks * 4) ^ (row & 7);
                const u32* pp = &Pw[wid][row * 64 + (c << 3)];
                const u32x4 w0 = *reinterpret_cast<const u32x4*>(pp);
                const u32x4 w1 = *reinterpret_cast<const u32x4*>(pp + 4);
                union { u16 s[8]; bf16x8 v; } uh, ul;
#pragma unroll
                for (int e = 0; e < 4; ++e) {
                    uh.s[e] = (u16)(w0[e] & 0xffffu); ul.s[e] = (u16)(w0[e] >> 16);
                    uh.s[e + 4] = (u16)(w1[e] & 0xffffu); ul.s[e + 4] = (u16)(w1[e] >> 16);
                }
                bf16x8 vbh[4], vbl[4];
#pragma unroll
                for (int n = 0; n < 4; ++n) {
                    const int vr = n * 16 + lrow;
                    const int idx = vr * 64 + (((lk + ks * 4) ^ (vr & 7)) << 3);
                    vbh[n] = *reinterpret_cast<const bf16x8*>(&sVh[buf][idx]);
                    vbl[n] = *reinterpret_cast<const bf16x8*>(&sVl[buf][idx]);
                }
                __builtin_amdgcn_s_setprio(1);
#pragma unroll
                for (int n = 0; n < 4; ++n) {
                    Oa[n] = mfma16(uh.v, vbh[n], Oa[n]);
                    Oa[n] = mfma16(ul.v, vbh[n], Oa[n]);
                    Oa[n] = mfma16(uh.v, vbl[n], Oa[n]);
                }
                __builtin_amdgcn_s_setprio(0);
            }
            LGKM0_BAR
            buf ^= 1;
        }
        // ---- writeout ----
#pragma unroll
        for (int r = 0; r < 4; ++r) {
            const float inv = 1.0f / lr[r];
            const int s = qw + (lk << 2) + r;
#pragma unroll
            for (int n = 0; n < 4; ++n) {
                const float o = Oa[n][r] * inv;
                const int d = hd * 64 + n * 16 + lrow;
                const size_t idx = ((size_t)b * SEQL + s) * DM + d;
                const u16 hi = f2bf(o);
                aoh[idx] = hi;
                aol[idx] = f2bf(o - bf2f(hi));
            }
        }
    }
}

// ---------------------------------------------------------------------------
extern "C" void kernel_launch(void* const* d_in, const int* in_sizes, int n_in,
                              void* d_out, int out_size, void* d_ws, size_t ws_size,
                              hipStream_t stream) {
    (void)in_sizes; (void)n_in; (void)out_size; (void)ws_size;
    const float* x  = (const float*)d_in[0];
    const float* Wq = (const float*)d_in[1];
    const float* Wk = (const float*)d_in[2];
    const float* Wv = (const float*)d_in[3];
    const float* Wo = (const float*)d_in[4];
    const float* W1 = (const float*)d_in[5];
    const float* W2 = (const float*)d_in[6];
    const float* W3 = (const float*)d_in[7];
    const float* g1 = (const float*)d_in[8];
    const float* g2 = (const float*)d_in[9];
    float* out = (float*)d_out;
    char* w = (char*)d_ws;
    const size_t MB = 1024ull * 1024ull;
    // Activations (80 MiB):
    u16* xnh = (u16*)(w + 0 * MB);
    u16* xnl = (u16*)(w + 8 * MB);
    u16* qh  = (u16*)(w + 16 * MB);
    u16* ql  = (u16*)(w + 24 * MB);
    u16* kh  = (u16*)(w + 32 * MB);
    u16* kl  = (u16*)(w + 40 * MB);
    u16* vth = (u16*)(w + 48 * MB);
    u16* vtl = (u16*)(w + 56 * MB);
    u16* aoh = (u16*)(w + 64 * MB);
    u16* aol = (u16*)(w + 72 * MB);
    u16* hh  = (u16*)(w + 16 * MB);   // aliases q..v after oproj
    u16* hl  = (u16*)(w + 48 * MB);
    // Pre-split weights (64 MiB at +80).
    u16* wsp = (u16*)(w + 80 * MB);
    u16* wqh = wsp;                  u16* wql = wqh + (1u << 20);
    u16* wkh = wql + (1u << 20);     u16* wkl = wkh + (1u << 20);
    u16* wvh = wkl + (1u << 20);     u16* wvl = wvh + (1u << 20);
    u16* woh = wvl + (1u << 20);     u16* wol = woh + (1u << 20);
    u16* w1h = wol + (1u << 20);     u16* w1l = w1h + (4u << 20);
    u16* w2h = w1l + (4u << 20);     u16* w2l = w2h + (4u << 20);
    u16* w3h = w2l + (4u << 20);     u16* w3l = w3h + (4u << 20);

    WJobs jobs;
    jobs.s[0] = Wq; jobs.h[0] = wqh; jobs.l[0] = wql;
    jobs.s[1] = Wk; jobs.h[1] = wkh; jobs.l[1] = wkl;
    jobs.s[2] = Wv; jobs.h[2] = wvh; jobs.l[2] = wvl;
    jobs.s[3] = Wo; jobs.h[3] = woh; jobs.l[3] = wol;
    jobs.s[4] = W1; jobs.h[4] = w1h; jobs.l[4] = w1l;
    jobs.s[5] = W2; jobs.h[5] = w2h; jobs.l[5] = w2l;
    jobs.s[6] = W3; jobs.h[6] = w3h; jobs.l[6] = w3l;
    k_splitw_all<<<8192, 256, 0, stream>>>(jobs);

    k_rmsnorm<<<dim3(MTOK / 4), 256, 0, stream>>>(x, g1, xnh, xnl);
    k_qkv<<<dim3(32, 24), 256, 0, stream>>>(xnh, xnl,
        wqh, wql, wkh, wkl, wvh, wvl, qh, ql, kh, kl, vth, vtl);
    k_attn<<<dim3(16, 32), 256, 0, stream>>>(qh, ql, kh, kl, vth, vtl, aoh, aol);
    k_oproj<<<dim3(32, 8), 256, 0, stream>>>(aoh, aol, woh, wol, x, out);
    k_rmsnorm<<<dim3(MTOK / 4), 256, 0, stream>>>(out, g2, xnh, xnl);
    k_ffn13<<<dim3(32, 32), 256, 0, stream>>>(xnh, xnl, w1h, w1l, w3h, w3l, hh, hl);
    k_ffn2<<<dim3(32, 8), 256, 0, stream>>>(hh, hl, w2h, w2l, out);
}

// Round 9
// 759.684 us; speedup vs baseline: 1.0041x; 1.0041x over previous
//
#include <hip/hip_runtime.h>
#include <hip/hip_bf16.h>

#define DM 1024
#define NH 16
#define DH 64
#define DFF 4096
#define NBATCH 2
#define SEQL 2048
#define MTOK (NBATCH*SEQL)

typedef float f32x4 __attribute__((ext_vector_type(4)));
typedef __bf16 bf16x8 __attribute__((ext_vector_type(8)));
typedef unsigned short u16;
typedef unsigned int u32;
typedef unsigned short u16x4 __attribute__((ext_vector_type(4)));
typedef unsigned short u16x8 __attribute__((ext_vector_type(8)));
typedef unsigned int u32x4 __attribute__((ext_vector_type(4)));

__device__ __forceinline__ u16 f2bf(float f) {
    u32 u = __builtin_bit_cast(u32, f);
    return (u16)((u + 0x7fffu + ((u >> 16) & 1u)) >> 16);
}
__device__ __forceinline__ float bf2f(u16 h) {
    return __builtin_bit_cast(float, (u32)h << 16);
}
__device__ __forceinline__ f32x4 mfma16(bf16x8 a, bf16x8 b, f32x4 c) {
    return __builtin_amdgcn_mfma_f32_16x16x32_bf16(a, b, c, 0, 0, 0);
}
// async global->LDS, 16B per lane. LDS dest = wave-uniform base + lane*16.
__device__ __forceinline__ void gload16(const void* g, void* l) {
    __builtin_amdgcn_global_load_lds(
        (const __attribute__((address_space(1))) unsigned int*)g,
        (__attribute__((address_space(3))) unsigned int*)l, 16, 0, 0);
}
// XCD swizzle kept ONLY for attn (per-XCD KV working set 4MB = fits L2).
// r8 evidence: applying it to GEMMs грew FETCH 164->288MB (working set
// per chunk = full A sweep 16MB >> L2) -> reverted for GEMMs.
__device__ __forceinline__ int xcd_swz(int p, int nwg) {
    return (p & 7) * (nwg >> 3) + (p >> 3);
}
// Counted-vmcnt barrier pairs (T4).
#define WAIT_VM8_BAR  { asm volatile("s_waitcnt vmcnt(8)" ::: "memory"); \
                        asm volatile("s_barrier" ::: "memory"); }
#define WAIT_VM6_BAR  { asm volatile("s_waitcnt vmcnt(6)" ::: "memory"); \
                        asm volatile("s_barrier" ::: "memory"); }
#define WAIT_VM0_BAR  { asm volatile("s_waitcnt vmcnt(0)" ::: "memory"); \
                        asm volatile("s_barrier" ::: "memory"); }
#define LGKM0_BAR     { asm volatile("s_waitcnt lgkmcnt(0)" ::: "memory"); \
                        asm volatile("s_barrier" ::: "memory"); }

// ---------------------------------------------------------------------------
// GEMM core (128x128, 4 waves): BK=32, dbuf, counted vmcnt(8).
// LDS swizzle (r6-verified, conflicts==0): 16B chunk c of row r stored at
// c ^ ((r>>1)&3); global source pre-swizzled (both-sides rule).
// Split fp32 = bf16_hi + bf16_lo; product via 3 MFMAs (drop lo*lo ~2^-18).
// ---------------------------------------------------------------------------
__device__ __forceinline__ void gemm_core(
    const u16* __restrict__ Ah, const u16* __restrict__ Al,
    const u16* __restrict__ Bh, const u16* __restrict__ Bl,
    int K, int m0, int n0,
    u16* lsAh, u16* lsAl, u16* lsBh, u16* lsBl,   // each [2][128*32]
    f32x4 acc[4][4])
{
    const int t = threadIdx.x;
    const int lane = t & 63;
    const int wv = t >> 6;
    const int wm = ((t >> 7) & 1) * 64;
    const int wn = ((t >> 6) & 1) * 64;
    const int lrow = lane & 15;
    const int lk = lane >> 4;
    const f32x4 FZ = {0.f, 0.f, 0.f, 0.f};
#pragma unroll
    for (int i = 0; i < 4; ++i)
#pragma unroll
        for (int j = 0; j < 4; ++j) acc[i][j] = FZ;

    const int NT = K >> 5;
    const int rsub = lane >> 2;
    const int gchk = ((lane & 3) ^ ((lane >> 3) & 3)) * 8;   // k-offset, elems
    const int rsw = (lk ^ ((lrow >> 1) & 3)) * 8;

    auto stage = [&](int buf, int kt) {
        const int k0 = kt << 5;
#pragma unroll
        for (int p = 0; p < 2; ++p) {
            const int seg = wv * 2 + p;   // 8 segments of 16 rows
            const int row = seg * 16 + rsub;
            const size_t sa = (size_t)(m0 + row) * K + k0 + gchk;
            const size_t sb = (size_t)(n0 + row) * K + k0 + gchk;
            const int d = buf * 4096 + seg * 512;
            gload16(Ah + sa, lsAh + d);
            gload16(Al + sa, lsAl + d);
            gload16(Bh + sb, lsBh + d);
            gload16(Bl + sb, lsBl + d);
        }
    };

    stage(0, 0);
    int buf = 0;
    for (int kt = 0; kt < NT; ++kt) {
        if (kt + 1 < NT) {
            stage(buf ^ 1, kt + 1);
            WAIT_VM8_BAR
        } else {
            WAIT_VM0_BAR
        }
        bf16x8 ah[4], al[4], bh[4], bl[4];
#pragma unroll
        for (int i = 0; i < 4; ++i) {
            const int ia = buf * 4096 + (wm + i * 16 + lrow) * 32 + rsw;
            ah[i] = *reinterpret_cast<const bf16x8*>(&lsAh[ia]);
            al[i] = *reinterpret_cast<const bf16x8*>(&lsAl[ia]);
            const int ib = buf * 4096 + (wn + i * 16 + lrow) * 32 + rsw;
            bh[i] = *reinterpret_cast<const bf16x8*>(&lsBh[ib]);
            bl[i] = *reinterpret_cast<const bf16x8*>(&lsBl[ib]);
        }
        __builtin_amdgcn_s_setprio(1);
#pragma unroll
        for (int i = 0; i < 4; ++i)
#pragma unroll
            for (int j = 0; j < 4; ++j) {
                acc[i][j] = mfma16(ah[i], bh[j], acc[i][j]);
                acc[i][j] = mfma16(al[i], bh[j], acc[i][j]);
                acc[i][j] = mfma16(ah[i], bl[j], acc[i][j]);
            }
        __builtin_amdgcn_s_setprio(0);
        LGKM0_BAR
        buf ^= 1;
    }
}

#define GEMM_LDS \
    __shared__ __align__(16) u16 lsAh[2 * 4096], lsAl[2 * 4096], \
                                 lsBh[2 * 4096], lsBl[2 * 4096];

// ---------------------------------------------------------------------------
// GEMM core (256x128, 8 waves = 4m x 2n): BK=32, dbuf, counted vmcnt(6).
// 6 staging loads/thread (vs 8 at 128^2); 2x A/B panel reuse. LDS 96KB,
// 1 block/CU = 2 waves/SIMD (same occupancy as the 128^2 core at 2 blocks).
// ---------------------------------------------------------------------------
__device__ __forceinline__ void gemm_core256(
    const u16* __restrict__ Ah, const u16* __restrict__ Al,
    const u16* __restrict__ Bh, const u16* __restrict__ Bl,
    int K, int m0, int n0,
    u16* lsAh, u16* lsAl,   // each [2][256*32]
    u16* lsBh, u16* lsBl,   // each [2][128*32]
    f32x4 acc[4][4])
{
    const int t = threadIdx.x;
    const int lane = t & 63;
    const int wv = t >> 6;                 // 0..7
    const int wm = (wv >> 1) * 64;         // 4 m-waves
    const int wn = (wv & 1) * 64;          // 2 n-waves
    const int lrow = lane & 15;
    const int lk = lane >> 4;
    const f32x4 FZ = {0.f, 0.f, 0.f, 0.f};
#pragma unroll
    for (int i = 0; i < 4; ++i)
#pragma unroll
        for (int j = 0; j < 4; ++j) acc[i][j] = FZ;

    const int NT = K >> 5;
    const int rsub = lane >> 2;
    const int gchk = ((lane & 3) ^ ((lane >> 3) & 3)) * 8;
    const int rsw = (lk ^ ((lrow >> 1) & 3)) * 8;

    auto stage = [&](int buf, int kt) {
        const int k0 = kt << 5;
        // A: 16 segs of 16 rows; wave handles segs wv and wv+8.
#pragma unroll
        for (int p = 0; p < 2; ++p) {
            const int seg = wv + p * 8;
            const int row = seg * 16 + rsub;
            const size_t sa = (size_t)(m0 + row) * K + k0 + gchk;
            const int d = buf * 8192 + seg * 512;
            gload16(Ah + sa, lsAh + d);
            gload16(Al + sa, lsAl + d);
        }
        // B: 8 segs of 16 rows; wave handles seg wv.
        {
            const int row = wv * 16 + rsub;
            const size_t sb = (size_t)(n0 + row) * K + k0 + gchk;
            const int d = buf * 4096 + wv * 512;
            gload16(Bh + sb, lsBh + d);
            gload16(Bl + sb, lsBl + d);
        }
    };

    stage(0, 0);
    int buf = 0;
    for (int kt = 0; kt < NT; ++kt) {
        if (kt + 1 < NT) {
            stage(buf ^ 1, kt + 1);
            WAIT_VM6_BAR
        } else {
            WAIT_VM0_BAR
        }
        bf16x8 ah[4], al[4], bh[4], bl[4];
#pragma unroll
        for (int i = 0; i < 4; ++i) {
            const int ia = buf * 8192 + (wm + i * 16 + lrow) * 32 + rsw;
            ah[i] = *reinterpret_cast<const bf16x8*>(&lsAh[ia]);
            al[i] = *reinterpret_cast<const bf16x8*>(&lsAl[ia]);
            const int ib = buf * 4096 + (wn + i * 16 + lrow) * 32 + rsw;
            bh[i] = *reinterpret_cast<const bf16x8*>(&lsBh[ib]);
            bl[i] = *reinterpret_cast<const bf16x8*>(&lsBl[ib]);
        }
        __builtin_amdgcn_s_setprio(1);
#pragma unroll
        for (int i = 0; i < 4; ++i)
#pragma unroll
            for (int j = 0; j < 4; ++j) {
                acc[i][j] = mfma16(ah[i], bh[j], acc[i][j]);
                acc[i][j] = mfma16(al[i], bh[j], acc[i][j]);
                acc[i][j] = mfma16(ah[i], bl[j], acc[i][j]);
            }
        __builtin_amdgcn_s_setprio(0);
        LGKM0_BAR
        buf ^= 1;
    }
}

#define GEMM_LDS256 \
    __shared__ __align__(16) u16 lsAh[2 * 8192], lsAl[2 * 8192], \
                                 lsBh[2 * 4096], lsBl[2 * 4096];

// C/D frag mapping (HW-verified m89): col = lane&15, row = (lane>>4)*4 + r
template <int WAVES, class F>
__device__ __forceinline__ void epilogue(const f32x4 acc[4][4], int m0, int n0, F f) {
    const int lane = threadIdx.x & 63;
    const int wv = (int)threadIdx.x >> 6;
    const int wm = (WAVES == 8 ? (wv >> 1) : ((wv >> 1) & 1)) * 64;
    const int wn = (wv & 1) * 64;
#pragma unroll
    for (int i = 0; i < 4; ++i)
#pragma unroll
        for (int j = 0; j < 4; ++j)
#pragma unroll
            for (int r = 0; r < 4; ++r) {
                const int m = m0 + wm + i * 16 + ((lane >> 4) << 2) + r;
                const int o = n0 + wn + j * 16 + (lane & 15);
                f(m, o, acc[i][j][r]);
            }
}

// ---------------------------------------------------------------------------
// Merged weight split: one launch for all 7 matrices.
struct WJobs { const float* s[7]; u16* h[7]; u16* l[7]; };
__global__ __launch_bounds__(256) void k_splitw_all(WJobs jobs)
{
    const int bid = blockIdx.x;
    int which, off;
    if (bid < 2048) { which = bid >> 9; off = bid & 511; }
    else { which = 4 + ((bid - 2048) >> 11); off = (bid - 2048) & 2047; }
    const float* __restrict__ src = jobs.s[which];
    u16* __restrict__ dh = jobs.h[which];
    u16* __restrict__ dl = jobs.l[which];
    const int i = (off * 256 + threadIdx.x) * 8;
    const f32x4 a = *reinterpret_cast<const f32x4*>(src + i);
    const f32x4 b = *reinterpret_cast<const f32x4*>(src + i + 4);
    u16x8 hh, ll;
#pragma unroll
    for (int e = 0; e < 4; ++e) {
        const u16 h0 = f2bf(a[e]);
        hh[e] = h0; ll[e] = f2bf(a[e] - bf2f(h0));
        const u16 h1 = f2bf(b[e]);
        hh[4 + e] = h1; ll[4 + e] = f2bf(b[e] - bf2f(h1));
    }
    *reinterpret_cast<u16x8*>(dh + i) = hh;
    *reinterpret_cast<u16x8*>(dl + i) = ll;
}

__global__ __launch_bounds__(256) void k_rmsnorm(
    const float* __restrict__ x, const float* __restrict__ g,
    u16* __restrict__ oh, u16* __restrict__ ol)
{
    const int row = blockIdx.x * 4 + (threadIdx.x >> 6);
    const int lane = threadIdx.x & 63;
    const float* xr = x + (size_t)row * DM;
    f32x4 v[4];
    float ss = 0.f;
#pragma unroll
    for (int j = 0; j < 4; ++j) {
        v[j] = *reinterpret_cast<const f32x4*>(&xr[(lane + j * 64) * 4]);
        ss += v[j][0] * v[j][0] + v[j][1] * v[j][1] + v[j][2] * v[j][2] + v[j][3] * v[j][3];
    }
#pragma unroll
    for (int off = 32; off > 0; off >>= 1) ss += __shfl_xor(ss, off, 64);
    const float sc = 1.0f / sqrtf(ss * (1.0f / (float)DM) + 1e-5f);
#pragma unroll
    for (int j = 0; j < 4; ++j) {
        const int c0 = (lane + j * 64) * 4;
        const f32x4 gv = *reinterpret_cast<const f32x4*>(&g[c0]);
        u16x4 hh, ll;
#pragma unroll
        for (int e = 0; e < 4; ++e) {
            const float y = v[j][e] * sc * gv[e];
            const u16 hi = f2bf(y);
            hh[e] = hi;
            ll[e] = f2bf(y - bf2f(hi));
        }
        *reinterpret_cast<u16x4*>(&oh[(size_t)row * DM + c0]) = hh;
        *reinterpret_cast<u16x4*>(&ol[(size_t)row * DM + c0]) = ll;
    }
}

// QKV (256x128 core): grid (16, 24). q,k in [B,H,S,dh]; v TRANSPOSED [B,H,dh,S].
__global__ __launch_bounds__(512, 1) void k_qkv(
    const u16* __restrict__ Ah, const u16* __restrict__ Al,
    const u16* __restrict__ swqh, const u16* __restrict__ swql,
    const u16* __restrict__ swkh, const u16* __restrict__ swkl,
    const u16* __restrict__ swvh, const u16* __restrict__ swvl,
    u16* __restrict__ qh, u16* __restrict__ ql, u16* __restrict__ kh, u16* __restrict__ kl,
    u16* __restrict__ vth, u16* __restrict__ vtl)
{
    GEMM_LDS256
    const int m0 = blockIdx.x * 256;
    const int ng = blockIdx.y * 128;
    const int proj = ng >> 10;
    const int n0 = ng & 1023;
    const u16* Bh = (proj == 0) ? swqh : ((proj == 1) ? swkh : swvh);
    const u16* Bl = (proj == 0) ? swql : ((proj == 1) ? swkl : swvl);
    f32x4 acc[4][4];
    gemm_core256(Ah, Al, Bh, Bl, DM, m0, n0, lsAh, lsAl, lsBh, lsBl, acc);
    if (proj < 2) {
        u16* oph = (proj == 0) ? qh : kh;
        u16* opl = (proj == 0) ? ql : kl;
        epilogue<8>(acc, m0, n0, [&](int m, int o, float val) {
            const int b = m >> 11, s = m & (SEQL - 1);
            const int hd = o >> 6, d = o & 63;
            const size_t idx = (((size_t)b * NH + hd) * SEQL + s) * DH + d;
            const u16 hi = f2bf(val);
            oph[idx] = hi;
            opl[idx] = f2bf(val - bf2f(hi));
        });
    } else {
        epilogue<8>(acc, m0, n0, [&](int m, int o, float val) {
            const int b = m >> 11, s = m & (SEQL - 1);
            const int hd = o >> 6, d = o & 63;
            const size_t idx = (((size_t)b * NH + hd) * DH + d) * SEQL + s;
            const u16 hi = f2bf(val);
            vth[idx] = hi;
            vtl[idx] = f2bf(val - bf2f(hi));
        });
    }
}

__global__ __launch_bounds__(256, 2) void k_oproj(
    const u16* __restrict__ Ah, const u16* __restrict__ Al,
    const u16* __restrict__ Bh, const u16* __restrict__ Bl,
    const float* __restrict__ xres, float* __restrict__ out)
{
    GEMM_LDS
    const int m0 = blockIdx.x * 128;
    const int n0 = blockIdx.y * 128;
    f32x4 acc[4][4];
    gemm_core(Ah, Al, Bh, Bl, DM, m0, n0, lsAh, lsAl, lsBh, lsBl, acc);
    epilogue<4>(acc, m0, n0, [&](int m, int o, float val) {
        const size_t idx = (size_t)m * DM + o;
        out[idx] = xres[idx] + val;
    });
}

// Fused FFN1+FFN3 (256x128 core): grid (16, 32).
__global__ __launch_bounds__(512, 1) void k_ffn13(
    const u16* __restrict__ Ah, const u16* __restrict__ Al,
    const u16* __restrict__ B1h, const u16* __restrict__ B1l,
    const u16* __restrict__ B3h, const u16* __restrict__ B3l,
    u16* __restrict__ hh, u16* __restrict__ hl)
{
    GEMM_LDS256
    const int m0 = blockIdx.x * 256;
    const int n0 = blockIdx.y * 128;
    f32x4 acc1[4][4], acc3[4][4];
    gemm_core256(Ah, Al, B1h, B1l, DM, m0, n0, lsAh, lsAl, lsBh, lsBl, acc1);
    gemm_core256(Ah, Al, B3h, B3l, DM, m0, n0, lsAh, lsAl, lsBh, lsBl, acc3);
    const int lane = threadIdx.x & 63;
    const int wv = (int)threadIdx.x >> 6;
    const int wm = (wv >> 1) * 64;
    const int wn = (wv & 1) * 64;
#pragma unroll
    for (int i = 0; i < 4; ++i)
#pragma unroll
        for (int j = 0; j < 4; ++j)
#pragma unroll
            for (int r = 0; r < 4; ++r) {
                const int m = m0 + wm + i * 16 + ((lane >> 4) << 2) + r;
                const int o = n0 + wn + j * 16 + (lane & 15);
                const float h1 = acc1[i][j][r];
                const float h3 = acc3[i][j][r];
                const float sg = 1.0f / (1.0f + expf(-h1));
                const float hv = h1 * sg * h3;
                const size_t idx = (size_t)m * DFF + o;
                const u16 hi = f2bf(hv);
                hh[idx] = hi;
                hl[idx] = f2bf(hv - bf2f(hi));
            }
}

__global__ __launch_bounds__(256, 2) void k_ffn2(
    const u16* __restrict__ Ah, const u16* __restrict__ Al,
    const u16* __restrict__ Bh, const u16* __restrict__ Bl,
    float* __restrict__ out)
{
    GEMM_LDS
    const int m0 = blockIdx.x * 128;
    const int n0 = blockIdx.y * 128;
    f32x4 acc[4][4];
    gemm_core(Ah, Al, Bh, Bl, DFF, m0, n0, lsAh, lsAl, lsBh, lsBl, acc);
    epilogue<4>(acc, m0, n0, [&](int m, int o, float val) {
        const size_t idx = (size_t)m * DM + o;
        out[idx] = out[idx] + val;
    });
}

// ---------------------------------------------------------------------------
// Flash attention. Logical grid (16 pairs, 32 bh); XCD swizzle gives each XCD
// 4 consecutive bh (4 MB KV = L2-resident). 4 waves x 16 q-rows; K [kv][d]
// and V^T [d][kv] staged via global_load_lds, dbuf, counted-vmcnt pipeline.
// ---------------------------------------------------------------------------
__global__ __launch_bounds__(256) void k_attn(
    const u16* __restrict__ gqh, const u16* __restrict__ gql,
    const u16* __restrict__ gkh, const u16* __restrict__ gkl,
    const u16* __restrict__ gvth, const u16* __restrict__ gvtl,
    u16* __restrict__ aoh, u16* __restrict__ aol)
{
    __shared__ __align__(16) u16 sKh[2][4096], sKl[2][4096], sVh[2][4096], sVl[2][4096];
    __shared__ __align__(16) u32 Pw[4][16 * 64];
    const int t = threadIdx.x, lane = t & 63, wid = t >> 6;
    const int lrow = lane & 15, lk = lane >> 4;
    const int swz = xcd_swz(blockIdx.y * 16 + blockIdx.x, 16 * 32);
    const int pr = swz & 15;
    const int bh = swz >> 4;
    const size_t base = (size_t)bh * SEQL * DH;
    const f32x4 FZ = {0.f, 0.f, 0.f, 0.f};
    const int b = bh >> 4, hd = bh & 15;

    auto stage = [&](int buf, int kvt) {
        const int kv0 = kvt << 6;
#pragma unroll
        for (int p = 0; p < 2; ++p) {
            const int seg = wid * 2 + p;            // 0..7, 8 rows each
            const int row = seg * 8 + (lane >> 3);
            const int g = (lane & 7) ^ (row & 7);
            const size_t sk = base + (size_t)(kv0 + row) * DH + g * 8;
            const size_t sv = base + (size_t)row * SEQL + kv0 + g * 8;
            gload16(gkh + sk, &sKh[buf][seg * 512]);
            gload16(gkl + sk, &sKl[buf][seg * 512]);
            gload16(gvth + sv, &sVh[buf][seg * 512]);
            gload16(gvtl + sv, &sVl[buf][seg * 512]);
        }
    };

    for (int hf = 0; hf < 2; ++hf) {
        const int qt = hf ? (31 - pr) : pr;
        const int qw = qt * 64 + wid * 16;
        bf16x8 Qh[2], Ql[2];
#pragma unroll
        for (int ks = 0; ks < 2; ++ks) {
            const size_t off = base + (size_t)(qw + lrow) * DH + ks * 32 + lk * 8;
            Qh[ks] = *reinterpret_cast<const bf16x8*>(&gqh[off]);
            Ql[ks] = *reinterpret_cast<const bf16x8*>(&gql[off]);
        }
        float mr[4], lr[4];
        f32x4 Oa[4];
#pragma unroll
        for (int r = 0; r < 4; ++r) { mr[r] = -1.0e30f; lr[r] = 0.f; }
#pragma unroll
        for (int n = 0; n < 4; ++n) Oa[n] = FZ;

        const int ntile = qt + 1;
        stage(0, 0);
        int buf = 0;
        for (int kvt = 0; kvt < ntile; ++kvt) {
            if (kvt + 1 < ntile) {
                stage(buf ^ 1, kvt + 1);
                WAIT_VM8_BAR
            } else {
                WAIT_VM0_BAR
            }
            const int kv0 = kvt << 6;
            // ---- QK^T ----
            f32x4 S[4];
#pragma unroll
            for (int nf = 0; nf < 4; ++nf) S[nf] = FZ;
#pragma unroll
            for (int ks = 0; ks < 2; ++ks) {
                bf16x8 kbh[4], kbl[4];
#pragma unroll
                for (int nf = 0; nf < 4; ++nf) {
                    const int row = nf * 16 + lrow;
                    const int idx = row * 64 + (((lk + ks * 4) ^ (row & 7)) << 3);
                    kbh[nf] = *reinterpret_cast<const bf16x8*>(&sKh[buf][idx]);
                    kbl[nf] = *reinterpret_cast<const bf16x8*>(&sKl[buf][idx]);
                }
                __builtin_amdgcn_s_setprio(1);
#pragma unroll
                for (int nf = 0; nf < 4; ++nf) {
                    S[nf] = mfma16(Qh[ks], kbh[nf], S[nf]);
                    S[nf] = mfma16(Ql[ks], kbh[nf], S[nf]);
                    S[nf] = mfma16(Qh[ks], kbl[nf], S[nf]);
                }
                __builtin_amdgcn_s_setprio(0);
            }
            // ---- online softmax (scale 1/8) ----
#pragma unroll
            for (int r = 0; r < 4; ++r) {
                const int qrow = qw + (lk << 2) + r;
                float rmx = -3.0e38f;
#pragma unroll
                for (int nf = 0; nf < 4; ++nf) {
                    const int col = kv0 + nf * 16 + lrow;
                    const float tv = (col <= qrow) ? S[nf][r] * 0.125f : -3.0e38f;
                    S[nf][r] = tv;
                    rmx = fmaxf(rmx, tv);
                }
#pragma unroll
                for (int off = 8; off > 0; off >>= 1) rmx = fmaxf(rmx, __shfl_xor(rmx, off, 16));
                const float mnew = fmaxf(mr[r], rmx);
                const float alpha = exp2f((mr[r] - mnew) * 1.44269504f);
                mr[r] = mnew;
                float rsum = 0.f;
#pragma unroll
                for (int nf = 0; nf < 4; ++nf) {
                    const float p = exp2f((S[nf][r] - mnew) * 1.44269504f);
                    S[nf][r] = p;
                    rsum += p;
                }
#pragma unroll
                for (int off = 8; off > 0; off >>= 1) rsum += __shfl_xor(rsum, off, 16);
                lr[r] = lr[r] * alpha + rsum;
#pragma unroll
                for (int n = 0; n < 4; ++n) Oa[n][r] *= alpha;
                const int prow = (lk << 2) + r;
#pragma unroll
                for (int nf = 0; nf < 4; ++nf) {
                    const float p = S[nf][r];
                    const u16 phi = f2bf(p);
                    const u16 plo = f2bf(p - bf2f(phi));
                    const int pcol = nf * 16 + lrow;
                    Pw[wid][prow * 64 + ((((pcol >> 3) ^ (prow & 7))) << 3) + (pcol & 7)] =
                        (u32)phi | ((u32)plo << 16);
                }
            }
            asm volatile("s_waitcnt lgkmcnt(0)" ::: "memory");
            // ---- P @ V (A-frag from Pw, B-frag from V^T tile) ----
#pragma unroll
            for (int ks = 0; ks < 2; ++ks) {
                const int row = lrow;
                const int c = (lk + ks * 4) ^ (row & 7);
                const u32* pp = &Pw[wid][row * 64 + (c << 3)];
                const u32x4 w0 = *reinterpret_cast<const u32x4*>(pp);
                const u32x4 w1 = *reinterpret_cast<const u32x4*>(pp + 4);
                union { u16 s[8]; bf16x8 v; } uh, ul;
#pragma unroll
                for (int e = 0; e < 4; ++e) {
                    uh.s[e] = (u16)(w0[e] & 0xffffu); ul.s[e] = (u16)(w0[e] >> 16);
                    uh.s[e + 4] = (u16)(w1[e] & 0xffffu); ul.s[e + 4] = (u16)(w1[e] >> 16);
                }
                bf16x8 vbh[4], vbl[4];
#pragma unroll
                for (int n = 0; n < 4; ++n) {
                    const int vr = n * 16 + lrow;
                    const int idx = vr * 64 + (((lk + ks * 4) ^ (vr & 7)) << 3);
                    vbh[n] = *reinterpret_cast<const bf16x8*>(&sVh[buf][idx]);
                    vbl[n] = *reinterpret_cast<const bf16x8*>(&sVl[buf][idx]);
                }
                __builtin_amdgcn_s_setprio(1);
#pragma unroll
                for (int n = 0; n < 4; ++n) {
                    Oa[n] = mfma16(uh.v, vbh[n], Oa[n]);
                    Oa[n] = mfma16(ul.v, vbh[n], Oa[n]);
                    Oa[n] = mfma16(uh.v, vbl[n], Oa[n]);
                }
                __builtin_amdgcn_s_setprio(0);
            }
            LGKM0_BAR
            buf ^= 1;
        }
        // ---- writeout ----
#pragma unroll
        for (int r = 0; r < 4; ++r) {
            const float inv = 1.0f / lr[r];
            const int s = qw + (lk << 2) + r;
#pragma unroll
            for (int n = 0; n < 4; ++n) {
                const float o = Oa[n][r] * inv;
                const int d = hd * 64 + n * 16 + lrow;
                const size_t idx = ((size_t)b * SEQL + s) * DM + d;
                const u16 hi = f2bf(o);
                aoh[idx] = hi;
                aol[idx] = f2bf(o - bf2f(hi));
            }
        }
    }
}

// ---------------------------------------------------------------------------
extern "C" void kernel_launch(void* const* d_in, const int* in_sizes, int n_in,
                              void* d_out, int out_size, void* d_ws, size_t ws_size,
                              hipStream_t stream) {
    (void)in_sizes; (void)n_in; (void)out_size; (void)ws_size;
    const float* x  = (const float*)d_in[0];
    const float* Wq = (const float*)d_in[1];
    const float* Wk = (const float*)d_in[2];
    const float* Wv = (const float*)d_in[3];
    const float* Wo = (const float*)d_in[4];
    const float* W1 = (const float*)d_in[5];
    const float* W2 = (const float*)d_in[6];
    const float* W3 = (const float*)d_in[7];
    const float* g1 = (const float*)d_in[8];
    const float* g2 = (const float*)d_in[9];
    float* out = (float*)d_out;
    char* w = (char*)d_ws;
    const size_t MB = 1024ull * 1024ull;
    // Activations (80 MiB):
    u16* xnh = (u16*)(w + 0 * MB);
    u16* xnl = (u16*)(w + 8 * MB);
    u16* qh  = (u16*)(w + 16 * MB);
    u16* ql  = (u16*)(w + 24 * MB);
    u16* kh  = (u16*)(w + 32 * MB);
    u16* kl  = (u16*)(w + 40 * MB);
    u16* vth = (u16*)(w + 48 * MB);
    u16* vtl = (u16*)(w + 56 * MB);
    u16* aoh = (u16*)(w + 64 * MB);
    u16* aol = (u16*)(w + 72 * MB);
    u16* hh  = (u16*)(w + 16 * MB);   // aliases q..v after oproj
    u16* hl  = (u16*)(w + 48 * MB);
    // Pre-split weights (64 MiB at +80).
    u16* wsp = (u16*)(w + 80 * MB);
    u16* wqh = wsp;                  u16* wql = wqh + (1u << 20);
    u16* wkh = wql + (1u << 20);     u16* wkl = wkh + (1u << 20);
    u16* wvh = wkl + (1u << 20);     u16* wvl = wvh + (1u << 20);
    u16* woh = wvl + (1u << 20);     u16* wol = woh + (1u << 20);
    u16* w1h = wol + (1u << 20);     u16* w1l = w1h + (4u << 20);
    u16* w2h = w1l + (4u << 20);     u16* w2l = w2h + (4u << 20);
    u16* w3h = w2l + (4u << 20);     u16* w3l = w3h + (4u << 20);

    WJobs jobs;
    jobs.s[0] = Wq; jobs.h[0] = wqh; jobs.l[0] = wql;
    jobs.s[1] = Wk; jobs.h[1] = wkh; jobs.l[1] = wkl;
    jobs.s[2] = Wv; jobs.h[2] = wvh; jobs.l[2] = wvl;
    jobs.s[3] = Wo; jobs.h[3] = woh; jobs.l[3] = wol;
    jobs.s[4] = W1; jobs.h[4] = w1h; jobs.l[4] = w1l;
    jobs.s[5] = W2; jobs.h[5] = w2h; jobs.l[5] = w2l;
    jobs.s[6] = W3; jobs.h[6] = w3h; jobs.l[6] = w3l;
    k_splitw_all<<<8192, 256, 0, stream>>>(jobs);

    k_rmsnorm<<<dim3(MTOK / 4), 256, 0, stream>>>(x, g1, xnh, xnl);
    k_qkv<<<dim3(16, 24), 512, 0, stream>>>(xnh, xnl,
        wqh, wql, wkh, wkl, wvh, wvl, qh, ql, kh, kl, vth, vtl);
    k_attn<<<dim3(16, 32), 256, 0, stream>>>(qh, ql, kh, kl, vth, vtl, aoh, aol);
    k_oproj<<<dim3(32, 8), 256, 0, stream>>>(aoh, aol, woh, wol, x, out);
    k_rmsnorm<<<dim3(MTOK / 4), 256, 0, stream>>>(out, g2, xnh, xnl);
    k_ffn13<<<dim3(16, 32), 512, 0, stream>>>(xnh, xnl, w1h, w1l, w3h, w3l, hh, hl);
    k_ffn2<<<dim3(32, 8), 256, 0, stream>>>(hh, hl, w2h, w2l, out);
}